// Round 1
// baseline (1907.642 us; speedup 1.0000x reference)
//
#include <hip/hip_runtime.h>
#include <stdint.h>

// Problem constants
#define TT 256      // timesteps per phase
#define BB 256      // batch
#define II 128      // input dim
#define SS 256      // state dim
#define RGRP 16     // row groups
#define CGRP 16     // col groups per row group (team size)
#define RB 16       // batch rows per block
#define CB 16       // state cols per block
#define NSTEP (2*TT)

typedef _Float16 h16;
typedef _Float16 half8 __attribute__((ext_vector_type(8)));
typedef float f32x4 __attribute__((ext_vector_type(4)));

#define SBP 264     // s_buf padded row stride (halves): 256+8 -> conflict-free b128
#define XBP 136     // xbuf padded row stride (halves): 128+8

__device__ __forceinline__ float sigmoidf_(float z) {
    return __builtin_amdgcn_rcpf(1.0f + __expf(-z));
}
__device__ __forceinline__ float tanhf_(float z) {
    // tanh(z) = 1 - 2/(1+exp(2z)); exact at +/-inf, ~1e-7 abs err
    return 1.0f - 2.0f * __builtin_amdgcn_rcpf(1.0f + __expf(2.0f * z));
}

struct Ptrs {
    const float *x;
    const float *Wi, *Ui, *Bi, *Wf, *Uf, *Bf, *Wo, *Uo, *Bo, *Wg, *Ug, *Bg;
    float* out;
    uint32_t* ws;
};

__global__ void lstm_zero_flags(uint32_t* flags) {
    flags[threadIdx.x] = 0u;
}

__global__ __launch_bounds__(256) void lstm_persist(Ptrs p) {
    const int blk  = blockIdx.x;
    const int r    = blk / CGRP;          // row group id
    const int c    = blk % CGRP;          // col group id
    const int tid  = threadIdx.x;
    const int wave = tid >> 6;            // gate: 0=i 1=f 2=o 3=g
    const int lane = tid & 63;
    const int lrow = lane & 15;           // A-row / B-col within tile
    const int lk8  = (lane >> 4) * 8;     // k sub-offset within 32-chunk
    const int r0   = r * RB;
    const int c0   = c * CB;
    const int erow = tid >> 4;            // elementwise (row,col) ownership
    const int ecol = tid & 15;

    __shared__ __align__(16) h16 s_buf[RB * SBP];
    __shared__ __align__(16) h16 xbuf[RB * XBP];
    __shared__ float zbuf[4][16][17];
    __shared__ float biasLds[4][16];

    uint32_t* xchg  = p.ws;                             // [2][RGRP][RB*128] dwords
    uint32_t* flags = p.ws + 2 * RGRP * RB * 128;       // [RGRP*CGRP]

    const float* Uptr[4] = {p.Ui, p.Uf, p.Uo, p.Ug};
    const float* Wptr[4] = {p.Wi, p.Wf, p.Wo, p.Wg};
    const float* Bptr[4] = {p.Bi, p.Bf, p.Bo, p.Bg};

    // ---- init ----
    if (tid < 64) biasLds[tid >> 4][tid & 15] = Bptr[tid >> 4][c0 + (tid & 15)];
    for (int idx = tid; idx < RB * SBP; idx += 256) s_buf[idx] = (h16)0.0f;

    // Preload B-operand fragments for this wave's gate into registers.
    // B layout (16x16x32): lane holds B[k=(lane>>4)*8+q][col=lane&15]
    const float* Ug = Uptr[wave];
    const float* Wg = Wptr[wave];
    half8 bU[8];
#pragma unroll
    for (int kc = 0; kc < 8; ++kc)
#pragma unroll
        for (int q = 0; q < 8; ++q)
            bU[kc][q] = (h16)Ug[(size_t)(kc * 32 + lk8 + q) * SS + c0 + lrow];
    half8 bW[4];
#pragma unroll
    for (int kc = 0; kc < 4; ++kc)
#pragma unroll
        for (int q = 0; q < 8; ++q)
            bW[kc][q] = (h16)Wg[(size_t)(kc * 32 + lk8 + q) * SS + c0 + lrow];

    float cst = 0.0f;   // cell state owned by this thread: (erow, ecol)

    __syncthreads();

    for (int n = 1; n <= NSTEP; ++n) {
        const bool enc = (n <= TT);

        // ---- stage x[t] tile (encode only) ----
        if (enc) {
            const int t = n - 1;
            const float* xp = p.x + ((size_t)t * BB + r0 + erow) * II + ecol * 8;
            float4 a = ((const float4*)xp)[0];
            float4 b = ((const float4*)xp)[1];
            half8 h;
            h[0]=(h16)a.x; h[1]=(h16)a.y; h[2]=(h16)a.z; h[3]=(h16)a.w;
            h[4]=(h16)b.x; h[5]=(h16)b.y; h[6]=(h16)b.z; h[7]=(h16)b.w;
            *(half8*)&xbuf[erow * XBP + ecol * 8] = h;
        }
        __syncthreads();

        // ---- MFMA: z[16rows,16cols] for gate `wave` ----
        f32x4 acc = {0.f, 0.f, 0.f, 0.f};
#pragma unroll
        for (int kc = 0; kc < 8; ++kc) {
            half8 a = *(const half8*)&s_buf[lrow * SBP + kc * 32 + lk8];
            acc = __builtin_amdgcn_mfma_f32_16x16x32_f16(a, bU[kc], acc, 0, 0, 0);
        }
        if (enc) {
#pragma unroll
            for (int kc = 0; kc < 4; ++kc) {
                half8 a = *(const half8*)&xbuf[lrow * XBP + kc * 32 + lk8];
                acc = __builtin_amdgcn_mfma_f32_16x16x32_f16(a, bW[kc], acc, 0, 0, 0);
            }
        }
        // C/D layout: col=lane&15, row=(lane>>4)*4+reg  (m89-verified)
#pragma unroll
        for (int q = 0; q < 4; ++q)
            zbuf[wave][(lane >> 4) * 4 + q][lrow] = acc[q];
        __syncthreads();

        // ---- elementwise gates / state update ----
        float zi = zbuf[0][erow][ecol] + biasLds[0][ecol];
        float zf = zbuf[1][erow][ecol] + biasLds[1][ecol];
        float zo = zbuf[2][erow][ecol] + biasLds[2][ecol];
        float zg = zbuf[3][erow][ecol] + biasLds[3][ecol];
        float ig = sigmoidf_(zi);
        float fg = sigmoidf_(zf);
        float og = sigmoidf_(zo);
        float gg = tanhf_(zg);
        cst = cst * fg + gg * ig;
        float sv = tanhf_(cst) * og;

        if (!enc) {
            const int d = n - TT - 1;
            p.out[((size_t)d * BB + r0 + erow) * SS + c0 + ecol] = og;
        }

        if (n < NSTEP) {
            // ---- publish own s slice (fp16, packed pairs), agent-scope ----
            float so = __shfl_xor(sv, 1);
            if ((tid & 1) == 0) {
                uint16_t lo = __builtin_bit_cast(uint16_t, (h16)sv);
                uint16_t hi = __builtin_bit_cast(uint16_t, (h16)so);
                uint32_t pk = (uint32_t)lo | ((uint32_t)hi << 16);
                uint32_t* dst = xchg + ((size_t)(n & 1) * RGRP + r) * (RB * 128)
                              + erow * 128 + c * 8 + (ecol >> 1);
                __hip_atomic_store(dst, pk, __ATOMIC_RELAXED, __HIP_MEMORY_SCOPE_AGENT);
            }
            // ensure data stores reached the coherence point before flag
            asm volatile("s_waitcnt vmcnt(0)" ::: "memory");
            __syncthreads();
            if (tid == 0)
                __hip_atomic_store(&flags[r * CGRP + c], (uint32_t)n,
                                   __ATOMIC_RELAXED, __HIP_MEMORY_SCOPE_AGENT);
            // spin until all 16 team slices for step n are published
            if (tid < CGRP) {
                while (__hip_atomic_load(&flags[r * CGRP + tid], __ATOMIC_RELAXED,
                                         __HIP_MEMORY_SCOPE_AGENT) < (uint32_t)n)
                    __builtin_amdgcn_s_sleep(1);
            }
            __syncthreads();
            // ---- gather full s_n for our 16 rows into s_buf ----
            uint32_t* src = xchg + ((size_t)(n & 1) * RGRP + r) * (RB * 128)
                          + erow * 128 + ecol * 8;
            uint32_t d0[8];
#pragma unroll
            for (int j = 0; j < 8; ++j)
                d0[j] = __hip_atomic_load(src + j, __ATOMIC_RELAXED,
                                          __HIP_MEMORY_SCOPE_AGENT);
            uint4* dst4 = (uint4*)&s_buf[erow * SBP + ecol * 16];
            dst4[0] = make_uint4(d0[0], d0[1], d0[2], d0[3]);
            dst4[1] = make_uint4(d0[4], d0[5], d0[6], d0[7]);
            __syncthreads();
        }
    }
}

extern "C" void kernel_launch(void* const* d_in, const int* in_sizes, int n_in,
                              void* d_out, int out_size, void* d_ws, size_t ws_size,
                              hipStream_t stream) {
    Ptrs p;
    p.x  = (const float*)d_in[0];
    p.Wi = (const float*)d_in[1];  p.Ui = (const float*)d_in[2];  p.Bi = (const float*)d_in[3];
    p.Wf = (const float*)d_in[4];  p.Uf = (const float*)d_in[5];  p.Bf = (const float*)d_in[6];
    p.Wo = (const float*)d_in[7];  p.Uo = (const float*)d_in[8];  p.Bo = (const float*)d_in[9];
    p.Wg = (const float*)d_in[10]; p.Ug = (const float*)d_in[11]; p.Bg = (const float*)d_in[12];
    p.out = (float*)d_out;
    p.ws  = (uint32_t*)d_ws;

    uint32_t* flags = p.ws + 2 * RGRP * RB * 128;
    hipLaunchKernelGGL(lstm_zero_flags, dim3(1), dim3(RGRP * CGRP), 0, stream, flags);

    void* args[] = {&p};
    hipLaunchCooperativeKernel(lstm_persist, dim3(RGRP * CGRP), dim3(256),
                               args, 0, stream);
}